// Round 1
// baseline (81.459 us; speedup 1.0000x reference)
//
#include <hip/hip_runtime.h>
#include <math.h>

#define NN 1024
#define NBB 16
#define NP 256
#define TT 80
#define EPS_LEN 1e-9f
#define EPS_DD 1e-12f

struct Shmem {
  float px[NP], py[NP], pz[NP];
  float segl[NP], cums[NP], t0[NP];
  float red[256];
  float md[4];
  int mi[4];
  int nv;
};

__device__ __forceinline__ int upper_bound256(const float* a, float v) {
  // first idx in [0,256) with a[idx] > v
  int lo = 0, hi = NP;
  while (lo < hi) { int mid = (lo + hi) >> 1; if (a[mid] > v) hi = mid; else lo = mid + 1; }
  return lo;
}

// n_valid for this (n,b); mask layout auto-detected (bool bytes vs 4-byte ints).
// byte[1] of the buffer: bool layout -> mask[0][0][1]=1 (lengths>=2); int32 -> high byte of elem0 = 0.
__device__ __forceinline__ int load_nv(const void* mask, size_t base, int tid, int* s_nv) {
  bool as_byte = ((const unsigned char*)mask)[1] != 0;
  int val;
  if (as_byte) val = (((const unsigned char*)mask)[base + tid] != 0) ? 1 : 0;
  else         val = (((const int*)mask)[base + tid] != 0) ? 1 : 0;
  unsigned long long bal = __ballot(val);
  if (tid == 0) *s_nv = 0;
  __syncthreads();
  if ((tid & 63) == 0) atomicAdd(s_nv, __popcll(bal));
  __syncthreads();
  return *s_nv;
}

// Evaluate one (boundary, direction) candidate. 256 threads.
// WRITE=false: *cost_out = sum_t ||pos[t]-proj[t]||.  WRITE=true: proj_out[t*3+k]=proj.
template<bool WRITE>
__device__ void eval_candidate(Shmem& S, const float* pos, const float* tcs,
                               int nv, int dir, float* cost_out, float* proj_out) {
  const int tid = threadIdx.x;
  const int lane = tid & 63, wid = tid >> 6;
  __syncthreads();  // protect LDS reuse across calls

  // dir==0: packed order; dir==1: reversed order
  float p0x = pos[0], p0y = pos[1], p0z = pos[2];
  float seglv = 0.f, t0v = 0.f, d2 = INFINITY;
  if (tid < nv - 1) {
    int ia = dir ? (nv - 1 - tid) : tid;
    int ib = dir ? (nv - 2 - tid) : (tid + 1);
    float ax = S.px[ia], ay = S.py[ia], az = S.pz[ia];
    float bx = S.px[ib], by = S.py[ib], bz = S.pz[ib];
    float vx = bx - ax, vy = by - ay, vz = bz - az;
    float n2 = vx*vx + vy*vy + vz*vz;
    seglv = fmaxf(sqrtf(n2), EPS_LEN);
    float t = ((p0x-ax)*vx + (p0y-ay)*vy + (p0z-az)*vz) / fmaxf(n2, EPS_DD);
    t = fminf(fmaxf(t, 0.f), 1.f);
    float qx = ax + t*vx, qy = ay + t*vy, qz = az + t*vz;
    float dx = p0x-qx, dy = p0y-qy, dz = p0z-qz;
    d2 = dx*dx + dy*dy + dz*dz;
    t0v = t;
  }
  S.segl[tid] = seglv;
  S.t0[tid] = t0v;

  // block-wide exclusive scan of seg lengths -> cums[0..255]
  float v = seglv;
  for (int d = 1; d < 64; d <<= 1) {
    float o = __shfl_up(v, d, 64);
    if (lane >= d) v += o;
  }
  if (lane == 63) S.red[wid] = v;
  __syncthreads();
  if (tid == 0) {
    float acc = 0.f;
    for (int w = 0; w < 4; ++w) { float tw = S.red[w]; S.red[w] = acc; acc += tw; }
  }
  __syncthreads();
  v += S.red[wid];
  if (tid == 0) S.cums[0] = 0.f;
  if (tid < NP - 1) S.cums[tid + 1] = v;

  // argmin of d2 with first-index tie-break -> entry segment
  float bd = d2; int bi = tid;
  for (int d = 32; d > 0; d >>= 1) {
    float od = __shfl_down(bd, d, 64);
    int oi = __shfl_down(bi, d, 64);
    if (od < bd || (od == bd && oi < bi)) { bd = od; bi = oi; }
  }
  if (lane == 0) { S.md[wid] = bd; S.mi[wid] = bi; }
  __syncthreads();
  if (tid == 0) {
    float b0 = S.md[0]; int i0 = S.mi[0];
    for (int w = 1; w < 4; ++w)
      if (S.md[w] < b0 || (S.md[w] == b0 && S.mi[w] < i0)) { b0 = S.md[w]; i0 = S.mi[w]; }
    S.mi[0] = i0;
  }
  __syncthreads();
  int seg0 = S.mi[0];
  float entry_s = S.cums[seg0] + S.t0[seg0] * S.segl[seg0];
  float total_s = S.cums[nv - 1];

  float my_d = 0.f;
  if (tid < TT) {
    float ts = entry_s + tcs[tid];
    ts = fminf(fmaxf(ts, 0.f), total_s);
    int j = upper_bound256(S.cums, ts) - 1;
    int jmax = nv - 2; if (jmax < 0) jmax = 0;
    j = j < 0 ? 0 : (j > jmax ? jmax : j);
    float sl = S.segl[j];
    float tl = (ts - S.cums[j]) / fmaxf(sl, EPS_LEN);
    tl = fminf(fmaxf(tl, 0.f), 1.f);
    int ia = dir ? (nv - 1 - j) : j;
    int ib = dir ? (nv - 2 - j) : (j + 1);
    float ax = S.px[ia], ay = S.py[ia], az = S.pz[ia];
    float bx = S.px[ib], by = S.py[ib], bz = S.pz[ib];
    float prx = ax + tl*(bx-ax), pry = ay + tl*(by-ay), prz = az + tl*(bz-az);
    if (WRITE) {
      proj_out[tid*3+0] = prx;
      proj_out[tid*3+1] = pry;
      proj_out[tid*3+2] = prz;
    } else {
      float dx = pos[tid*3+0]-prx, dy = pos[tid*3+1]-pry, dz = pos[tid*3+2]-prz;
      my_d = sqrtf(dx*dx+dy*dy+dz*dz);
    }
  }
  if (!WRITE) {
    __syncthreads();
    S.red[tid] = (tid < TT) ? my_d : 0.f;
    __syncthreads();
    if (tid == 0) {
      float acc = 0.f;
      for (int i = 0; i < TT; ++i) acc += S.red[i];
      *cost_out = acc;
    }
  }
  __syncthreads();
}

// K1: per-n cumulative trajectory arc length (serial cumsum = numpy order)
__global__ __launch_bounds__(128)
void traj_cs_kernel(const float* __restrict__ traj, float* __restrict__ tcs) {
  const int n = blockIdx.x;
  const int t = threadIdx.x;
  __shared__ float s_seg[TT];
  const float* p = traj + (size_t)n * TT * 3;
  if (t < TT - 1) {
    float dx = p[(t+1)*3+0]-p[t*3+0];
    float dy = p[(t+1)*3+1]-p[t*3+1];
    float dz = p[(t+1)*3+2]-p[t*3+2];
    s_seg[t] = sqrtf(dx*dx+dy*dy+dz*dz);
  }
  __syncthreads();
  if (t == 0) {
    float acc = 0.f;
    float* o = tcs + (size_t)n * TT;
    o[0] = 0.f;
    for (int i = 0; i < TT-1; ++i) { acc += s_seg[i]; o[i+1] = acc; }
  }
}

// K2: per-(n,b) block -> cost for both directions
__global__ __launch_bounds__(256)
void cand_cost_kernel(const float* __restrict__ traj, const float* __restrict__ rp,
                      const void* __restrict__ mask, const float* __restrict__ tcs,
                      float* __restrict__ cost) {
  __shared__ Shmem S;
  const int nb = blockIdx.x;
  const int n = nb / NBB;
  const int tid = threadIdx.x;
  const float* p = rp + (size_t)nb * NP * 3;
  S.px[tid] = p[tid*3+0];
  S.py[tid] = p[tid*3+1];
  S.pz[tid] = p[tid*3+2];
  int nv = load_nv(mask, (size_t)nb * NP, tid, &S.nv);
  if (nv < 2) {
    if (tid == 0) { cost[nb*2+0] = INFINITY; cost[nb*2+1] = INFINITY; }
    return;
  }
  const float* pos = traj + (size_t)n * TT * 3;
  const float* tc = tcs + (size_t)n * TT;
  for (int dir = 0; dir < 2; ++dir)
    eval_candidate<false>(S, pos, tc, nv, dir, &cost[nb*2+dir], nullptr);
}

// K3: per-n block -> argmin over 32 candidates, recompute winner, write out
__global__ __launch_bounds__(256)
void winner_kernel(const float* __restrict__ traj, const float* __restrict__ rp,
                   const void* __restrict__ mask, const float* __restrict__ tcs,
                   const float* __restrict__ cost, float* __restrict__ out) {
  __shared__ Shmem S;
  __shared__ int s_best;
  const int n = blockIdx.x;
  const int tid = threadIdx.x;
  if (tid == 0) {
    const float* c = cost + (size_t)n * NBB * 2;
    float bc = INFINITY; int bi = -1;
    for (int i = 0; i < NBB*2; ++i) if (c[i] < bc) { bc = c[i]; bi = i; }
    s_best = bi;
  }
  __syncthreads();
  int best = s_best;
  const float* pos = traj + (size_t)n * TT * 3;
  float* o = out + (size_t)n * TT * 3;
  if (best < 0) {  // no valid candidate: passthrough
    for (int i = tid; i < TT*3; i += 256) o[i] = pos[i];
    return;
  }
  int b = best >> 1, dir = best & 1;
  const int nbi = n * NBB + b;
  const float* p = rp + (size_t)nbi * NP * 3;
  S.px[tid] = p[tid*3+0];
  S.py[tid] = p[tid*3+1];
  S.pz[tid] = p[tid*3+2];
  int nv = load_nv(mask, (size_t)nbi * NP, tid, &S.nv);
  eval_candidate<true>(S, pos, tcs + (size_t)n * TT, nv, dir, nullptr, o);
}

extern "C" void kernel_launch(void* const* d_in, const int* in_sizes, int n_in,
                              void* d_out, int out_size, void* d_ws, size_t ws_size,
                              hipStream_t stream) {
  const float* traj = (const float*)d_in[0];
  const float* rp   = (const float*)d_in[1];
  const void*  mask = d_in[2];
  float* tcs  = (float*)d_ws;                    // N*T floats
  float* cost = tcs + (size_t)NN * TT;           // N*NB*2 floats
  float* out  = (float*)d_out;

  hipLaunchKernelGGL(traj_cs_kernel, dim3(NN), dim3(128), 0, stream, traj, tcs);
  hipLaunchKernelGGL(cand_cost_kernel, dim3(NN * NBB), dim3(256), 0, stream,
                     traj, rp, mask, tcs, cost);
  hipLaunchKernelGGL(winner_kernel, dim3(NN), dim3(256), 0, stream,
                     traj, rp, mask, tcs, cost, out);
}

// Round 2
// 59.458 us; speedup vs baseline: 1.3700x; 1.3700x over previous
//
#include <hip/hip_runtime.h>
#include <math.h>

#define NN 1024
#define NBB 16
#define NP 256
#define TT 80
#define EPS_LEN 1e-9f
#define EPS_DD 1e-12f

struct Sh {
  float px[NP], py[NP], pz[NP];
  float segl[NP], cums[NP], t0[NP];
  float wsum[4];
  float amd[4]; int amf[4], aml[4];
  float redf[4];
  float entry[2];
  float total;
  int nv;
};

__device__ __forceinline__ int upper_bound256(const float* a, float v) {
  // first idx with a[idx] > v
  int lo = 0, hi = NP;
  while (lo < hi) { int mid = (lo + hi) >> 1; if (a[mid] > v) hi = mid; else lo = mid + 1; }
  return lo;
}
__device__ __forceinline__ int lower_bound256(const float* a, float v) {
  // first idx with a[idx] >= v
  int lo = 0, hi = NP;
  while (lo < hi) { int mid = (lo + hi) >> 1; if (a[mid] >= v) hi = mid; else lo = mid + 1; }
  return lo;
}

// n_valid; mask layout auto-detect (bool bytes vs 4-byte ints):
// byte[1]: bool layout -> mask[0][0][1]=1 (lengths>=2); int32 -> high byte of elem0 = 0.
__device__ __forceinline__ int load_nv(const void* mask, size_t base, int tid, int* s_nv) {
  bool as_byte = ((const unsigned char*)mask)[1] != 0;
  int val;
  if (as_byte) val = (((const unsigned char*)mask)[base + tid] != 0) ? 1 : 0;
  else         val = (((const int*)mask)[base + tid] != 0) ? 1 : 0;
  unsigned long long bal = __ballot(val);
  if (tid == 0) *s_nv = 0;
  __syncthreads();
  if ((tid & 63) == 0) atomicAdd(s_nv, __popcll(bal));
  __syncthreads();
  return *s_nv;
}

// Fused both-direction evaluation. Requires pts in S and nv>=2.
// WRITE=false: cost2[0]=fwd cost, cost2[1]=rev cost.
// WRITE=true : group wdir's timestep threads write proj to out[t*3+k].
template<bool WRITE>
__device__ void eval_fused(Sh& S, const float* __restrict__ pos,
                           const float* __restrict__ tcs, int nv,
                           float* cost2, int wdir, float* out) {
  const int tid = threadIdx.x;
  const int lane = tid & 63, wid = tid >> 6;

  // ---- forward segment pass (rev derives from it) ----
  float p0x = pos[0], p0y = pos[1], p0z = pos[2];
  float seglv = 0.f, t0v = 0.f, d2 = INFINITY;
  bool valid = tid < nv - 1;
  if (valid) {
    float ax = S.px[tid],   ay = S.py[tid],   az = S.pz[tid];
    float bx = S.px[tid+1], by = S.py[tid+1], bz = S.pz[tid+1];
    float vx = bx - ax, vy = by - ay, vz = bz - az;
    float n2 = vx*vx + vy*vy + vz*vz;
    seglv = fmaxf(sqrtf(n2), EPS_LEN);
    float t = ((p0x-ax)*vx + (p0y-ay)*vy + (p0z-az)*vz) / fmaxf(n2, EPS_DD);
    t = fminf(fmaxf(t, 0.f), 1.f);
    float qx = ax + t*vx, qy = ay + t*vy, qz = az + t*vz;
    float dx = p0x-qx, dy = p0y-qy, dz = p0z-qz;
    d2 = dx*dx + dy*dy + dz*dz;
    t0v = t;
  }
  S.segl[tid] = seglv;
  S.t0[tid] = t0v;

  // ---- block exclusive scan -> cums ----
  float v = seglv;
  for (int d = 1; d < 64; d <<= 1) {
    float o = __shfl_up(v, d, 64);
    if (lane >= d) v += o;
  }
  if (lane == 63) S.wsum[wid] = v;
  __syncthreads();
  if (tid == 0) {
    float acc = 0.f;
    for (int w = 0; w < 4; ++w) { float tw = S.wsum[w]; S.wsum[w] = acc; acc += tw; }
  }
  __syncthreads();
  v += S.wsum[wid];
  if (tid == 0) S.cums[0] = 0.f;
  if (tid < NP - 1) S.cums[tid + 1] = v;

  // ---- combined argmin: first-min (fwd entry) and last-min (rev entry) ----
  float bd = d2; int fi = tid, li = tid;
  for (int d = 32; d > 0; d >>= 1) {
    float od = __shfl_down(bd, d, 64);
    int ofi = __shfl_down(fi, d, 64);
    int oli = __shfl_down(li, d, 64);
    if (od < bd) { bd = od; fi = ofi; li = oli; }
    else if (od == bd) { fi = min(fi, ofi); li = max(li, oli); }
  }
  if (lane == 0) { S.amd[wid] = bd; S.amf[wid] = fi; S.aml[wid] = li; }
  __syncthreads();
  if (tid == 0) {
    float b0 = S.amd[0]; int f0 = S.amf[0], l0 = S.aml[0];
    for (int w = 1; w < 4; ++w) {
      float bw = S.amd[w];
      if (bw < b0) { b0 = bw; f0 = S.amf[w]; l0 = S.aml[w]; }
      else if (bw == b0) { f0 = min(f0, S.amf[w]); l0 = max(l0, S.aml[w]); }
    }
    float Tot = S.cums[nv - 1];
    S.total = Tot;
    S.entry[0] = S.cums[f0] + S.t0[f0] * S.segl[f0];
    S.entry[1] = (Tot - S.cums[l0 + 1]) + (1.f - S.t0[l0]) * S.segl[l0];
  }
  __syncthreads();

  // ---- timestep phase: threads 0-127 fwd, 128-255 rev ----
  const int grp = tid >> 7;
  const int t = tid & 127;
  const float Tot = S.total;
  const int jmax = nv - 2;
  float my_d = 0.f;
  if (t < TT) {
    float ts = S.entry[grp] + tcs[t];
    ts = fminf(fmaxf(ts, 0.f), Tot);
    int ia, ib;
    float tl;
    if (grp == 0) {
      int j = upper_bound256(S.cums, ts) - 1;
      j = j < 0 ? 0 : (j > jmax ? jmax : j);
      tl = (ts - S.cums[j]) / fmaxf(S.segl[j], EPS_LEN);
      ia = j; ib = j + 1;
    } else {
      float sp = Tot - ts;
      int lb = lower_bound256(S.cums, sp);
      int j = nv - 1 - lb;
      j = j < 0 ? 0 : (j > jmax ? jmax : j);
      float base = Tot - S.cums[nv - 1 - j];
      tl = (ts - base) / fmaxf(S.segl[nv - 2 - j], EPS_LEN);
      ia = nv - 1 - j; ib = nv - 2 - j;
    }
    tl = fminf(fmaxf(tl, 0.f), 1.f);
    float ax = S.px[ia], ay = S.py[ia], az = S.pz[ia];
    float bx = S.px[ib], by = S.py[ib], bz = S.pz[ib];
    float prx = ax + tl*(bx-ax), pry = ay + tl*(by-ay), prz = az + tl*(bz-az);
    if (WRITE) {
      if (grp == wdir) {
        out[t*3+0] = prx; out[t*3+1] = pry; out[t*3+2] = prz;
      }
    } else {
      float dx = pos[t*3+0]-prx, dy = pos[t*3+1]-pry, dz = pos[t*3+2]-prz;
      my_d = sqrtf(dx*dx+dy*dy+dz*dz);
    }
  }
  if (!WRITE) {
    // shuffle-tree sum within each warp; warps 0-1 = fwd, 2-3 = rev
    for (int d = 32; d > 0; d >>= 1) my_d += __shfl_down(my_d, d, 64);
    if (lane == 0) S.redf[wid] = my_d;
    __syncthreads();
    if (tid == 0) {
      cost2[0] = S.redf[0] + S.redf[1];
      cost2[1] = S.redf[2] + S.redf[3];
    }
  }
}

// K1: per-n cumulative trajectory arc length (serial cumsum = numpy order)
__global__ __launch_bounds__(128)
void traj_cs_kernel(const float* __restrict__ traj, float* __restrict__ tcs) {
  const int n = blockIdx.x;
  const int t = threadIdx.x;
  __shared__ float s_seg[TT];
  const float* p = traj + (size_t)n * TT * 3;
  if (t < TT - 1) {
    float dx = p[(t+1)*3+0]-p[t*3+0];
    float dy = p[(t+1)*3+1]-p[t*3+1];
    float dz = p[(t+1)*3+2]-p[t*3+2];
    s_seg[t] = sqrtf(dx*dx+dy*dy+dz*dz);
  }
  __syncthreads();
  if (t == 0) {
    float acc = 0.f;
    float* o = tcs + (size_t)n * TT;
    o[0] = 0.f;
    for (int i = 0; i < TT-1; ++i) { acc += s_seg[i]; o[i+1] = acc; }
  }
}

// K2: per-(n,b) block -> both-direction costs in one pass
__global__ __launch_bounds__(256)
void fused_cost_kernel(const float* __restrict__ traj, const float* __restrict__ rp,
                       const void* __restrict__ mask, const float* __restrict__ tcs,
                       float* __restrict__ cost) {
  __shared__ Sh S;
  const int nb = blockIdx.x;
  const int n = nb / NBB;
  const int tid = threadIdx.x;
  const float* p = rp + (size_t)nb * NP * 3;
  S.px[tid] = p[tid*3+0];
  S.py[tid] = p[tid*3+1];
  S.pz[tid] = p[tid*3+2];
  int nv = load_nv(mask, (size_t)nb * NP, tid, &S.nv);
  if (nv < 2) {
    if (tid == 0) { cost[nb*2+0] = INFINITY; cost[nb*2+1] = INFINITY; }
    return;
  }
  eval_fused<false>(S, traj + (size_t)n * TT * 3, tcs + (size_t)n * TT, nv,
                    &cost[nb*2], 0, nullptr);
}

// K3: per-n block -> argmin over 32 candidates, recompute winner, write out
__global__ __launch_bounds__(256)
void winner_kernel(const float* __restrict__ traj, const float* __restrict__ rp,
                   const void* __restrict__ mask, const float* __restrict__ tcs,
                   const float* __restrict__ cost, float* __restrict__ out) {
  __shared__ Sh S;
  __shared__ int s_best;
  const int n = blockIdx.x;
  const int tid = threadIdx.x;
  if (tid == 0) {
    const float* c = cost + (size_t)n * NBB * 2;
    float bc = INFINITY; int bi = -1;
    for (int i = 0; i < NBB*2; ++i) if (c[i] < bc) { bc = c[i]; bi = i; }
    s_best = bi;
  }
  __syncthreads();
  int best = s_best;
  const float* pos = traj + (size_t)n * TT * 3;
  float* o = out + (size_t)n * TT * 3;
  if (best < 0) {  // no valid candidate: passthrough
    for (int i = tid; i < TT*3; i += 256) o[i] = pos[i];
    return;
  }
  int b = best >> 1, dir = best & 1;
  const int nbi = n * NBB + b;
  const float* p = rp + (size_t)nbi * NP * 3;
  S.px[tid] = p[tid*3+0];
  S.py[tid] = p[tid*3+1];
  S.pz[tid] = p[tid*3+2];
  int nv = load_nv(mask, (size_t)nbi * NP, tid, &S.nv);
  eval_fused<true>(S, pos, tcs + (size_t)n * TT, nv, nullptr, dir, o);
}

extern "C" void kernel_launch(void* const* d_in, const int* in_sizes, int n_in,
                              void* d_out, int out_size, void* d_ws, size_t ws_size,
                              hipStream_t stream) {
  const float* traj = (const float*)d_in[0];
  const float* rp   = (const float*)d_in[1];
  const void*  mask = d_in[2];
  float* tcs  = (float*)d_ws;                    // N*T floats
  float* cost = tcs + (size_t)NN * TT;           // N*NB*2 floats
  float* out  = (float*)d_out;

  hipLaunchKernelGGL(traj_cs_kernel, dim3(NN), dim3(128), 0, stream, traj, tcs);
  hipLaunchKernelGGL(fused_cost_kernel, dim3(NN * NBB), dim3(256), 0, stream,
                     traj, rp, mask, tcs, cost);
  hipLaunchKernelGGL(winner_kernel, dim3(NN), dim3(256), 0, stream,
                     traj, rp, mask, tcs, cost, out);
}

// Round 3
// 40.647 us; speedup vs baseline: 2.0041x; 1.4628x over previous
//
#include <hip/hip_runtime.h>
#include <math.h>

#define NN 1024
#define NBB 16
#define NP 256
#define TT 80
#define EPS_LEN 1e-9f
#define EPS_DD 1e-12f

// Wave-synchronous LDS fence: order prior ds_writes before subsequent reads
// within one wave (no __syncthreads needed — LDS is partitioned per wave).
__device__ __forceinline__ void lds_fence() {
  __builtin_amdgcn_wave_barrier();
  asm volatile("s_waitcnt lgkmcnt(0)" ::: "memory");
  __builtin_amdgcn_wave_barrier();
}

// n_valid for one (n,b), computed wave-wide (uniform result, no LDS).
// Mask layout auto-detect: byte[1] of buffer != 0 -> bool bytes (mask[0][0][1]
// is true since lengths>=2); int32 layout -> byte 1 of elem0 == 0.
__device__ __forceinline__ int wave_nv(const void* mask, size_t base, int lane) {
  bool as_byte = ((const unsigned char*)mask)[1] != 0;
  int nv = 0;
  if (as_byte) {
    uchar4 v = ((const uchar4*)((const unsigned char*)mask + base))[lane];
    nv += __popcll(__ballot(v.x != 0));
    nv += __popcll(__ballot(v.y != 0));
    nv += __popcll(__ballot(v.z != 0));
    nv += __popcll(__ballot(v.w != 0));
  } else {
    int4 v = ((const int4*)((const int*)mask + base))[lane];
    nv += __popcll(__ballot(v.x != 0));
    nv += __popcll(__ballot(v.y != 0));
    nv += __popcll(__ballot(v.z != 0));
    nv += __popcll(__ballot(v.w != 0));
  }
  return nv;
}

// One wave evaluates one (n,b): both directions fused.
// MODE 0: lane0 writes cost2[0]=fwd, cost2[1]=rev.  MODE 1: write dir=wdir proj to out.
template<int MODE>
__device__ void eval_wave(float* px, float* py, float* pz, float* cums,
                          const float* __restrict__ pos, const float* __restrict__ tcs,
                          const float4* __restrict__ p4, int nv,
                          float* __restrict__ cost2, int wdir, float* __restrict__ out) {
  const int lane = threadIdx.x & 63;
  const int j0 = lane * 4;

  // ---- load 4 points/lane (48B contiguous), stage to LDS ----
  float4 A = p4[lane*3+0], B = p4[lane*3+1], C = p4[lane*3+2];
  float x[5], y[5], z[5];
  x[0]=A.x; y[0]=A.y; z[0]=A.z;
  x[1]=A.w; y[1]=B.x; z[1]=B.y;
  x[2]=B.z; y[2]=B.w; z[2]=C.x;
  x[3]=C.y; y[3]=C.z; z[3]=C.w;
  x[4]=__shfl_down(x[0],1,64); y[4]=__shfl_down(y[0],1,64); z[4]=__shfl_down(z[0],1,64);
  #pragma unroll
  for (int k=0;k<4;k++){ px[j0+k]=x[k]; py[j0+k]=y[k]; pz[j0+k]=z[k]; }

  // ---- segment pass: seg length, projection of pos[0], fused argmin ----
  float p0x=pos[0], p0y=pos[1], p0z=pos[2];
  float cpre[4];
  float run = 0.f;
  float bdf=INFINITY, btf=0.f; int bjf=j0;   // first-min
  float bdl=INFINITY, btl=0.f; int bjl=j0;   // last-min
  #pragma unroll
  for (int k=0;k<4;k++){
    bool valid = (j0+k) < nv-1;
    float vx=x[k+1]-x[k], vy=y[k+1]-y[k], vz=z[k+1]-z[k];
    float n2 = vx*vx+vy*vy+vz*vz;
    float sl = valid ? fmaxf(sqrtf(n2), EPS_LEN) : 0.f;
    float t = ((p0x-x[k])*vx+(p0y-y[k])*vy+(p0z-z[k])*vz)/fmaxf(n2,EPS_DD);
    t = fminf(fmaxf(t,0.f),1.f);
    float qx=x[k]+t*vx, qy=y[k]+t*vy, qz=z[k]+t*vz;
    float dx=p0x-qx, dy=p0y-qy, dz=p0z-qz;
    float d2 = valid ? (dx*dx+dy*dy+dz*dz) : INFINITY;
    if (d2 <  bdf){bdf=d2; bjf=j0+k; btf=t;}
    if (d2 <= bdl){bdl=d2; bjl=j0+k; btl=t;}
    run += sl; cpre[k]=run;
  }

  // ---- wave exclusive scan of per-lane totals -> cums ----
  float inc = run;
  #pragma unroll
  for (int d=1;d<64;d<<=1){ float o=__shfl_up(inc,d,64); if(lane>=d) inc+=o; }
  float excl = inc - run;
  if (lane==0) cums[0]=0.f;
  #pragma unroll
  for (int k=0;k<4;k++){ int idx=j0+k+1; if(idx<NP) cums[idx]=excl+cpre[k]; }

  // ---- wave argmin butterfly (first-min for fwd, last-min for rev) ----
  #pragma unroll
  for (int d=1;d<64;d<<=1){
    float od=__shfl_xor(bdf,d,64); int oj=__shfl_xor(bjf,d,64); float ot=__shfl_xor(btf,d,64);
    if (od<bdf || (od==bdf && oj<bjf)){bdf=od;bjf=oj;btf=ot;}
    float od2=__shfl_xor(bdl,d,64); int oj2=__shfl_xor(bjl,d,64); float ot2=__shfl_xor(btl,d,64);
    if (od2<bdl || (od2==bdl && oj2>bjl)){bdl=od2;bjl=oj2;btl=ot2;}
  }

  lds_fence();  // cums/pts writes -> visible to cross-lane reads below

  const float Tot = cums[nv-1];
  float slf = cums[bjf+1]-cums[bjf];
  float entry0 = cums[bjf] + btf*slf;
  float sll = cums[bjl+1]-cums[bjl];
  float entry1 = (Tot - cums[bjl+1]) + (1.f-btl)*sll;

  // ---- timestep phase: 160 tasks (80 fwd + 80 rev) over passes ----
  const int jmaxv = nv-2;
  float accf=0.f, accr=0.f;
  const int NPASS = (MODE==0)?3:2;
  #pragma unroll
  for (int p=0;p<NPASS;p++){
    int task = p*64 + lane;
    int dir, t; bool act;
    if (MODE==0){ act = task<2*TT; dir = task>=TT; t = dir ? task-TT : task; }
    else        { act = task<TT;   dir = wdir;     t = task; }
    if (act){
      float ts = (dir ? entry1 : entry0) + tcs[t];
      ts = fminf(fmaxf(ts,0.f),Tot);
      float v = dir ? (Tot-ts) : ts;
      int lo=0, hi=NP;
      #pragma unroll
      for (int s=0;s<8;s++){
        int mid=(lo+hi)>>1;
        float cv = cums[mid];
        bool cond = dir ? (cv>=v) : (cv>v);
        if (cond) hi=mid; else lo=mid+1;
      }
      int ia, ib; float tl;
      if (!dir){
        int j = lo-1; j = j<0?0:(j>jmaxv?jmaxv:j);
        tl = (ts - cums[j]) / fmaxf(cums[j+1]-cums[j], EPS_LEN);
        ia=j; ib=j+1;
      } else {
        int j = nv-1-lo; j = j<0?0:(j>jmaxv?jmaxv:j);
        int l2 = nv-1-j;
        float base = Tot - cums[l2];
        tl = (ts-base)/fmaxf(cums[l2]-cums[l2-1], EPS_LEN);
        ia=l2; ib=l2-1;
      }
      tl = fminf(fmaxf(tl,0.f),1.f);
      float ax=px[ia], ay=py[ia], az=pz[ia];
      float bx=px[ib], by=py[ib], bz=pz[ib];
      float prx=ax+tl*(bx-ax), pry=ay+tl*(by-ay), prz=az+tl*(bz-az);
      if (MODE==1){
        out[t*3+0]=prx; out[t*3+1]=pry; out[t*3+2]=prz;
      } else {
        float dx=pos[t*3+0]-prx, dy=pos[t*3+1]-pry, dz=pos[t*3+2]-prz;
        float dd=sqrtf(dx*dx+dy*dy+dz*dz);
        if (dir) accr+=dd; else accf+=dd;
      }
    }
  }
  if (MODE==0){
    #pragma unroll
    for (int d=32;d>0;d>>=1){ accf+=__shfl_down(accf,d,64); accr+=__shfl_down(accr,d,64); }
    if (lane==0){ cost2[0]=accf; cost2[1]=accr; }
  }
}

// K1: per-n trajectory cum arc length, one wave per n (tree scan)
__global__ __launch_bounds__(256)
void traj_cs_kernel(const float* __restrict__ traj, float* __restrict__ tcs) {
  const int wid = threadIdx.x>>6, lane = threadIdx.x&63;
  const int n = blockIdx.x*4 + wid;
  const float* p = traj + (size_t)n*TT*3;
  float* o = tcs + (size_t)n*TT;
  // segs t=0..78; lanes cover t=lane and (lane<15) t=64+lane
  float dx=p[(lane+1)*3+0]-p[lane*3+0];
  float dy=p[(lane+1)*3+1]-p[lane*3+1];
  float dz=p[(lane+1)*3+2]-p[lane*3+2];
  float sA = sqrtf(dx*dx+dy*dy+dz*dz);
  float incA = sA;
  #pragma unroll
  for (int d=1;d<64;d<<=1){ float ov=__shfl_up(incA,d,64); if(lane>=d) incA+=ov; }
  o[lane+1] = incA;                       // tcs[1..64]
  float tot = __shfl(incA, 63, 64);
  float sB = 0.f;
  if (lane<15){
    int t = 64+lane;
    float ex=p[(t+1)*3+0]-p[t*3+0];
    float ey=p[(t+1)*3+1]-p[t*3+1];
    float ez=p[(t+1)*3+2]-p[t*3+2];
    sB = sqrtf(ex*ex+ey*ey+ez*ez);
  }
  float incB = sB;
  #pragma unroll
  for (int d=1;d<64;d<<=1){ float ov=__shfl_up(incB,d,64); if(lane>=d) incB+=ov; }
  if (lane<15) o[65+lane] = tot + incB;   // tcs[65..79]
  if (lane==0) o[0] = 0.f;
}

// K2: one wave per (n,b) -> both-direction costs
__global__ __launch_bounds__(256)
void fused_cost_kernel(const float* __restrict__ traj, const float* __restrict__ rp,
                       const void* __restrict__ mask, const float* __restrict__ tcs,
                       float* __restrict__ cost) {
  __shared__ float spx[4][NP], spy[4][NP], spz[4][NP], scums[4][NP];
  const int wid = threadIdx.x>>6, lane = threadIdx.x&63;
  const int nb = blockIdx.x*4 + wid;
  const int n = nb / NBB;
  int nv = wave_nv(mask, (size_t)nb*NP, lane);
  if (nv < 2){
    if (lane==0){ cost[nb*2+0]=INFINITY; cost[nb*2+1]=INFINITY; }
    return;
  }
  eval_wave<0>(spx[wid],spy[wid],spz[wid],scums[wid],
               traj+(size_t)n*TT*3, tcs+(size_t)n*TT,
               (const float4*)(rp+(size_t)nb*NP*3), nv,
               cost+(size_t)nb*2, 0, nullptr);
}

// K3: one wave per n -> argmin over 32 candidates, recompute winner, write out
__global__ __launch_bounds__(256)
void winner_kernel(const float* __restrict__ traj, const float* __restrict__ rp,
                   const void* __restrict__ mask, const float* __restrict__ tcs,
                   const float* __restrict__ cost, float* __restrict__ out) {
  __shared__ float spx[4][NP], spy[4][NP], spz[4][NP], scums[4][NP];
  const int wid = threadIdx.x>>6, lane = threadIdx.x&63;
  const int n = blockIdx.x*4 + wid;
  const float* c = cost + (size_t)n*NBB*2;
  float bc = (lane<NBB*2) ? c[lane] : INFINITY;
  int bi = (lane<NBB*2) ? lane : 64;
  #pragma unroll
  for (int d=1;d<64;d<<=1){
    float oc=__shfl_xor(bc,d,64); int oi=__shfl_xor(bi,d,64);
    if (oc<bc || (oc==bc && oi<bi)){bc=oc;bi=oi;}
  }
  const float* pos = traj + (size_t)n*TT*3;
  float* o = out + (size_t)n*TT*3;
  if (bc == INFINITY){  // no valid candidate: passthrough
    if (lane < 60) ((float4*)o)[lane] = ((const float4*)pos)[lane];
    return;
  }
  int b = bi>>1, dir = bi&1;
  const size_t nbi = (size_t)n*NBB + b;
  int nv = wave_nv(mask, nbi*NP, lane);
  eval_wave<1>(spx[wid],spy[wid],spz[wid],scums[wid],
               pos, tcs+(size_t)n*TT,
               (const float4*)(rp+nbi*NP*3), nv,
               nullptr, dir, o);
}

extern "C" void kernel_launch(void* const* d_in, const int* in_sizes, int n_in,
                              void* d_out, int out_size, void* d_ws, size_t ws_size,
                              hipStream_t stream) {
  const float* traj = (const float*)d_in[0];
  const float* rp   = (const float*)d_in[1];
  const void*  mask = d_in[2];
  float* tcs  = (float*)d_ws;                    // N*T floats
  float* cost = tcs + (size_t)NN * TT;           // N*NB*2 floats
  float* out  = (float*)d_out;

  hipLaunchKernelGGL(traj_cs_kernel, dim3(NN/4), dim3(256), 0, stream, traj, tcs);
  hipLaunchKernelGGL(fused_cost_kernel, dim3(NN*NBB/4), dim3(256), 0, stream,
                     traj, rp, mask, tcs, cost);
  hipLaunchKernelGGL(winner_kernel, dim3(NN/4), dim3(256), 0, stream,
                     traj, rp, mask, tcs, cost, out);
}